// Round 23
// baseline (224.050 us; speedup 1.0000x reference)
//
#include <hip/hip_runtime.h>
#include <hip/hip_bf16.h>
#include <math.h>

#define NL 4
#define DMODEL 256
#define NH 8
#define FFDIM 1024
#define BB 4
#define SS 1024
#define HDIM 32
#define MROWS (BB * SS)   // 4096
#define LN_EPS 1e-5f

typedef __bf16 bf16x8 __attribute__((ext_vector_type(8)));
typedef float f32x4 __attribute__((ext_vector_type(4)));
typedef short s16x4 __attribute__((ext_vector_type(4)));
typedef unsigned int u32;

__device__ __forceinline__ ushort f2bf(float f) {
    uint u = __builtin_bit_cast(uint, f);
    u += 0x7fff + ((u >> 16) & 1);          // round-to-nearest-even
    return (ushort)(u >> 16);
}
__device__ __forceinline__ uint pack2(float a, float b) {
    return (uint)f2bf(a) | ((uint)f2bf(b) << 16);
}

// XCD-chunked block swizzle (T1).  nwg % 8 == 0 -> bijective.
__device__ __forceinline__ int xcd_swz(int bid, int nwg) {
    return (bid & 7) * (nwg >> 3) + (bid >> 3);
}

// counted vmcnt wait (T4): allow N newest loads outstanding; older ones done.
template<int N> __device__ __forceinline__ void vmcnt_wait() {
    asm volatile("s_waitcnt vmcnt(%0)" :: "n"(N) : "memory");
}
// raw barrier: NO implicit vmcnt(0) drain (unlike __syncthreads()).
__device__ __forceinline__ void raw_barrier() {
    asm volatile("s_barrier" ::: "memory");
}
__device__ __forceinline__ void lgkm0() {
    asm volatile("s_waitcnt lgkmcnt(0)" ::: "memory");
}

// async global->LDS, 16B per lane (wave-uniform LDS base + lane*16 layout)
__device__ __forceinline__ void async_ld16(const void* g, void* l) {
    __builtin_amdgcn_global_load_lds(
        (const __attribute__((address_space(1))) u32*)g,
        (__attribute__((address_space(3))) u32*)l, 16, 0, 0);
}

// ds_read_b64_tr_b16: per-lane byte addr A -> 4 bf16 at A, A+32B, A+64B, A+96B
#if __has_builtin(__builtin_amdgcn_ds_read_tr16_b64)
#define TR_BUILTIN 1
#else
#define TR_BUILTIN 0
#endif

__device__ __forceinline__ s16x4 tr16(const ushort* p) {
    __attribute__((address_space(3))) s16x4* ap =
        (__attribute__((address_space(3))) s16x4*)p;
#if TR_BUILTIN
    return __builtin_amdgcn_ds_read_tr16_b64(ap);
#else
    s16x4 r;
    asm volatile("ds_read_b64_tr_b16 %0, %1" : "=v"(r) : "v"(ap) : "memory");
    return r;
#endif
}
__device__ __forceinline__ void tr_fence() {
#if !TR_BUILTIN
    asm volatile("s_waitcnt lgkmcnt(0)" ::: "memory");
    __builtin_amdgcn_sched_barrier(0);
#endif
}

// ---------------------------------------------------------------------------
// All weight transposes in one dispatch. Flat tile id -> {weight, tile}.
// ---------------------------------------------------------------------------
__global__ __launch_bounds__(256)
void wconv_all(const float* __restrict__ qkv_w, const float* __restrict__ fc_w,
               const float* __restrict__ ff1_w, const float* __restrict__ ff2_w,
               ushort* __restrict__ wq, ushort* __restrict__ wfc,
               ushort* __restrict__ wf1, ushort* __restrict__ wf2)
{
    const int l = blockIdx.z;
    int t = blockIdx.x;
    const float* src; ushort* dst; int K, N, nx;
    if (t < 192)      {          src = qkv_w; dst = wq;  K = 256;  N = 768;  nx = 24; }
    else if (t < 256) { t -= 192; src = fc_w;  dst = wfc; K = 256;  N = 256;  nx = 8; }
    else if (t < 512) { t -= 256; src = ff1_w; dst = wf1; K = 256;  N = 1024; nx = 32; }
    else              { t -= 512; src = ff2_w; dst = wf2; K = 1024; N = 256;  nx = 8; }
    src += (size_t)l * K * N;
    dst += (size_t)l * K * N;
    const int n0 = (t % nx) * 32, k0 = (t / nx) * 32;

    __shared__ ushort tt[32][33];
    const int tn = threadIdx.x & 31, tk8 = threadIdx.x >> 5;
    #pragma unroll
    for (int i = 0; i < 4; ++i)
        tt[tn][tk8 + i * 8] = f2bf(src[(size_t)(k0 + tk8 + i * 8) * N + n0 + tn]);
    __syncthreads();
    #pragma unroll
    for (int i = 0; i < 4; ++i)
        dst[(size_t)(n0 + tk8 + i * 8) * K + k0 + tn] = tt[tk8 + i * 8][tn];
}

// ---------------------------------------------------------------------------
// x_in fp32 -> x fp32 (d_out residual stream) + x_bf bf16 mirror
// ---------------------------------------------------------------------------
__global__ __launch_bounds__(256)
void convert_x(const float* __restrict__ xin, float* __restrict__ x,
               ushort* __restrict__ xb)
{
    const size_t i = ((size_t)blockIdx.x * 256 + threadIdx.x) * 4;
    const float4 v = *reinterpret_cast<const float4*>(xin + i);
    *reinterpret_cast<float4*>(x + i) = v;
    uint2 p = make_uint2(pack2(v.x, v.y), pack2(v.z, v.w));
    *reinterpret_cast<uint2*>(xb + i) = p;
}

// ---------------------------------------------------------------------------
// MFMA GEMM, 2-phase dbuf, counted vmcnt + raw barriers, LDS swizzle + XCD
// swizzle (r13/r14 verified).  Per-layer qkv.
// ---------------------------------------------------------------------------
template<int BM, int BN, int WM, int WN, int ACT, int OBF>
__global__ __launch_bounds__(256)
void gemm_mfma(const ushort* __restrict__ A, const ushort* __restrict__ WT,
               const float* __restrict__ bias, float* __restrict__ Cf,
               ushort* __restrict__ Cb, int N, int K)
{
    constexpr int BK = 64;
    constexpr int WR = BM / WM;
    constexpr int WC = BN / WN;
    constexpr int MR = WR / 16, NR = WC / 16;
    constexpr int LSTG = BM / 32 + BN / 32;
    __shared__ __align__(16) ushort As[2][BM * BK];
    __shared__ __align__(16) ushort Bs[2][BN * BK];

    const int tid = threadIdx.x;
    const int lin = blockIdx.y * gridDim.x + blockIdx.x;
    const int work = xcd_swz(lin, gridDim.x * gridDim.y);
    const int m0 = (work / gridDim.x) * BM, n0 = (work % gridDim.x) * BN;
    const int wid = tid >> 6, lane = tid & 63;
    const int g = lane >> 4, c = lane & 15;
    const int wr = wid / WN, wc = wid % WN;

    auto stage = [&](int buf, int k0) {
        #pragma unroll
        for (int it = 0; it < (BM * BK * 2) / 4096; ++it) {
            const int o = tid * 16 + it * 4096;
            const int r = o >> 7;
            const int cb = (o & 127) ^ ((r & 7) << 4);
            async_ld16(A + (size_t)(m0 + r) * K + k0 + (cb >> 1),
                       (char*)&As[buf][0] + o);
        }
        #pragma unroll
        for (int it = 0; it < (BN * BK * 2) / 4096; ++it) {
            const int o = tid * 16 + it * 4096;
            const int r = o >> 7;
            const int cb = (o & 127) ^ ((r & 7) << 4);
            async_ld16(WT + (size_t)(n0 + r) * K + k0 + (cb >> 1),
                       (char*)&Bs[buf][0] + o);
        }
    };

    f32x4 acc[MR][NR] = {};

    stage(0, 0);

    int cur = 0;
    for (int k0 = 0; k0 < K; k0 += BK, cur ^= 1) {
        if (k0 + BK < K) { stage(cur ^ 1, k0 + BK); vmcnt_wait<LSTG>(); }
        else             { vmcnt_wait<0>(); }
        raw_barrier();

        #pragma unroll
        for (int ks = 0; ks < 2; ++ks) {
            bf16x8 af[MR], bfr[NR];
            #pragma unroll
            for (int mi = 0; mi < MR; ++mi) {
                const int row = wr * WR + mi * 16 + c;
                af[mi] = *(const bf16x8*)((const char*)&As[cur][0]
                    + row * 128 + ((ks * 64 + g * 16) ^ ((row & 7) << 4)));
            }
            #pragma unroll
            for (int ni = 0; ni < NR; ++ni) {
                const int row = wc * WC + ni * 16 + c;
                bfr[ni] = *(const bf16x8*)((const char*)&Bs[cur][0]
                    + row * 128 + ((ks * 64 + g * 16) ^ ((row & 7) << 4)));
            }
            #pragma unroll
            for (int mi = 0; mi < MR; ++mi)
                #pragma unroll
                for (int ni = 0; ni < NR; ++ni)
                    acc[mi][ni] = __builtin_amdgcn_mfma_f32_16x16x32_bf16(
                        af[mi], bfr[ni], acc[mi][ni], 0, 0, 0);
        }
        raw_barrier();
    }

    float bv[NR];
    #pragma unroll
    for (int ni = 0; ni < NR; ++ni)
        bv[ni] = bias[n0 + wc * WC + ni * 16 + c];

    #pragma unroll
    for (int mi = 0; mi < MR; ++mi) {
        #pragma unroll
        for (int j = 0; j < 4; ++j) {
            const int row = m0 + wr * WR + mi * 16 + g * 4 + j;
            #pragma unroll
            for (int ni = 0; ni < NR; ++ni) {
                float v = acc[mi][ni][j] + bv[ni];
                if (ACT) v = fmaxf(v, 0.f);
                const int col = n0 + wc * WC + ni * 16 + c;
                if (OBF) Cb[(size_t)row * N + col] = f2bf(v);
                else     Cf[(size_t)row * N + col] = v;
            }
        }
    }
}

// ---------------------------------------------------------------------------
// Fused MLP-chain v4 (r20 verified optimum): 8 COMPUTE waves (512 thr), each
// wave owns 32 output columns.  Double-buffered Bs, two raw barriers/step,
// depth-1 counted vmcnt with stage-before-wait ordering.  2 waves/SIMD.
// ---------------------------------------------------------------------------
__global__ __launch_bounds__(512)
void mlp_fused(const ushort* __restrict__ Aattn, const ushort* __restrict__ Wfc,
               const float* __restrict__ bfc, const float* __restrict__ g1,
               const float* __restrict__ be1, const ushort* __restrict__ W1,
               const float* __restrict__ b1, const ushort* __restrict__ W2,
               const float* __restrict__ b2, const float* __restrict__ g2,
               const float* __restrict__ be2, float* __restrict__ x,
               ushort* __restrict__ xb)
{
    __shared__ __align__(16) ushort As[2][16 * 64];     // 4KB
    __shared__ __align__(16) ushort Bs[2][256 * 64];    // 64KB
    __shared__ __align__(16) ushort ybf[16 * 256];      // 8KB  (swizzled)
    __shared__ __align__(16) ushort hbuf[16 * 1024];    // 32KB (swizzled)
    __shared__ float rsum[8][16], rsq[8][16], mval[16], ival[16];

    const int tid = threadIdx.x;
    const int m0 = blockIdx.x * 16;
    const int wid = tid >> 6, lane = tid & 63;
    const int g = lane >> 4, c = lane & 15;

    auto stageB = [&](int buf, const ushort* src, int ldk) {
        #pragma unroll
        for (int it = 0; it < 4; ++it) {        // 512 thr x 4 x 16B = 32KB
            const int o = tid * 16 + it * 8192;
            const int r = o >> 7;
            const int cb = (o & 127) ^ ((r & 7) << 4);
            async_ld16(src + (size_t)r * ldk + (cb >> 1), (char*)&Bs[buf][0] + o);
        }
    };
    auto stageA = [&](int buf, int k0) {
        if (tid < 128) {
            const int o = tid * 16;
            const int r = o >> 7;
            const int cb = (o & 127) ^ ((r & 7) << 4);
            async_ld16(Aattn + (size_t)(m0 + r) * 256 + k0 + (cb >> 1),
                       (char*)&As[buf][0] + o);
        }
    };

    f32x4 acc[2] = {};

    // ================= phase 1: fc (K=256, 4 steps) =================
    stageA(0, 0); stageB(0, Wfc, 256);
    int cur = 0;
    #pragma unroll
    for (int k = 0; k < 4; ++k, cur ^= 1) {
        if (k < 3) {
            stageA(cur ^ 1, (k + 1) * 64);
            stageB(cur ^ 1, Wfc + (k + 1) * 64, 256);
            if (tid < 128) vmcnt_wait<5>(); else vmcnt_wait<4>();
        } else {
            stageB(cur ^ 1, W1, 256);           // prefetch ff1 step 0
            vmcnt_wait<4>();
        }
        raw_barrier();
        #pragma unroll
        for (int ks = 0; ks < 2; ++ks) {
            const bf16x8 af = *(const bf16x8*)((const char*)&As[cur][0]
                + c * 128 + ((ks * 64 + g * 16) ^ ((c & 7) << 4)));
            #pragma unroll
            for (int ni = 0; ni < 2; ++ni) {
                const int row = wid * 32 + ni * 16 + c;
                const bf16x8 bf = *(const bf16x8*)((const char*)&Bs[cur][0]
                    + row * 128 + ((ks * 64 + g * 16) ^ ((row & 7) << 4)));
                acc[ni] = __builtin_amdgcn_mfma_f32_16x16x32_bf16(af, bf, acc[ni], 0, 0, 0);
            }
        }
        raw_barrier();
    }
    // cur == 0; ff1 step0 staged in buf 0.

    // ---- LN1 epilogue: y = LN(acc + bfc + x_res); res regs + ybf LDS
    float res[2][4];
    {
        float bv[2], gl[2], bl[2];
        #pragma unroll
        for (int ni = 0; ni < 2; ++ni) {
            const int col = wid * 32 + ni * 16 + c;
            bv[ni] = bfc[col]; gl[ni] = g1[col]; bl[ni] = be1[col];
        }
        #pragma unroll
        for (int j = 0; j < 4; ++j) {
            const int row = g * 4 + j;
            float s = 0.f;
            #pragma unroll
            for (int ni = 0; ni < 2; ++ni) {
                const int col = wid * 32 + ni * 16 + c;
                float vv = acc[ni][j] + bv[ni] + x[(size_t)(m0 + row) * 256 + col];
                acc[ni][j] = vv;
                s += vv;
            }
            #pragma unroll
            for (int off = 1; off < 16; off <<= 1) s += __shfl_xor(s, off);
            if (c == 0) rsum[wid][row] = s;
        }
        __syncthreads();
        if (tid < 16)
            mval[tid] = (rsum[0][tid] + rsum[1][tid] + rsum[2][tid] + rsum[3][tid]
                       + rsum[4][tid] + rsum[5][tid] + rsum[6][tid] + rsum[7][tid])
                        * (1.f / 256);
        __syncthreads();
        #pragma unroll
        for (int j = 0; j < 4; ++j) {
            const int row = g * 4 + j;
            const float mean = mval[row];
            float q = 0.f;
            #pragma unroll
            for (int ni = 0; ni < 2; ++ni) {
                const float d = acc[ni][j] - mean;
                q += d * d;
            }
            #pragma unroll
            for (int off = 1; off < 16; off <<= 1) q += __shfl_xor(q, off);
            if (c == 0) rsq[wid][row] = q;
        }
        __syncthreads();
        if (tid < 16) {
            const float q = rsq[0][tid] + rsq[1][tid] + rsq[2][tid] + rsq[3][tid]
                          + rsq[4][tid] + rsq[5][tid] + rsq[6][tid] + rsq[7][tid];
            ival[tid] = rsqrtf(q * (1.f / 256) + LN_EPS);
        }
        __syncthreads();
        #pragma unroll
        for (int j = 0; j < 4; ++j) {
            const int row = g * 4 + j;
            const float mean = mval[row], inv = ival[row];
            #pragma unroll
            for (int ni = 0; ni < 2; ++ni) {
                const int col = wid * 32 + ni * 16 + c;
                const float y = (acc[ni][j] - mean) * inv * gl[ni] + bl[ni];
                res[ni][j] = y;
                const int byteo = row * 512 + ((col * 2) ^ ((row & 7) << 4));
                *(ushort*)((char*)ybf + byteo) = f2bf(y);
                acc[ni][j] = 0.f;
            }
        }
    }
    lgkm0();
    raw_barrier();          // ybf visible to all waves

    // ================= phase 2: ff1 (4 nt-tiles x 4 k-steps) =================
    #pragma unroll 1
    for (int s = 0; s < 16; ++s, cur ^= 1) {
        const int kk = s & 3;
        if (s < 15) {
            const int s2 = s + 1;
            stageB(cur ^ 1, W1 + (size_t)((s2 >> 2) * 256) * 256 + (s2 & 3) * 64, 256);
            vmcnt_wait<4>();
        } else {
            stageB(cur ^ 1, W2, 1024);          // prefetch ff2 step 0
            vmcnt_wait<4>();
        }
        raw_barrier();
        #pragma unroll
        for (int ks = 0; ks < 2; ++ks) {
            const int kbyte = (kk * 64 + ks * 32 + g * 8) * 2;
            const bf16x8 af = *(const bf16x8*)((const char*)ybf
                + c * 512 + (kbyte ^ ((c & 7) << 4)));
            #pragma unroll
            for (int ni = 0; ni < 2; ++ni) {
                const int row = wid * 32 + ni * 16 + c;
                const bf16x8 bf = *(const bf16x8*)((const char*)&Bs[cur][0]
                    + row * 128 + ((ks * 64 + g * 16) ^ ((row & 7) << 4)));
                acc[ni] = __builtin_amdgcn_mfma_f32_16x16x32_bf16(af, bf, acc[ni], 0, 0, 0);
            }
        }
        raw_barrier();
        if (kk == 3) {      // h epilogue for this nt-tile
            const int nt = s >> 2;
            #pragma unroll
            for (int j = 0; j < 4; ++j) {
                const int row = g * 4 + j;
                #pragma unroll
                for (int ni = 0; ni < 2; ++ni) {
                    const int col = nt * 256 + wid * 32 + ni * 16 + c;
                    const float h = fmaxf(acc[ni][j] + b1[col], 0.f);
                    const int byteo = row * 2048 + (((col & 1023) * 2) ^ ((row & 7) << 4));
                    *(ushort*)((char*)hbuf + byteo) = f2bf(h);
                    acc[ni][j] = 0.f;
                }
            }
        }
    }
    lgkm0();
    raw_barrier();          // hbuf visible

    // ================= phase 3: ff2 (K=1024, 16 steps) =================
    #pragma unroll 1
    for (int s = 0; s < 16; ++s, cur ^= 1) {
        if (s < 15) { stageB(cur ^ 1, W2 + (s + 1) * 64, 1024); vmcnt_wait<4>(); }
        else        { vmcnt_wait<0>(); }
        raw_barrier();
        #pragma unroll
        for (int ks = 0; ks < 2; ++ks) {
            const int kbyte = (s * 64 + ks * 32 + g * 8) * 2;
            const bf16x8 af = *(const bf16x8*)((const char*)hbuf
                + c * 2048 + (kbyte ^ ((c & 7) << 4)));
            #pragma unroll
            for (int ni = 0; ni < 2; ++ni) {
                const int row = wid * 32 + ni * 16 + c;
                const bf16x8 bf = *(const bf16x8*)((const char*)&Bs[cur][0]
                    + row * 128 + ((ks * 64 + g * 16) ^ ((row & 7) << 4)));
                acc[ni] = __builtin_amdgcn_mfma_f32_16x16x32_bf16(af, bf, acc[ni], 0, 0, 0);
            }
        }
        raw_barrier();
    }

    // ---- LN2 epilogue: x = LN(acc + b2 + res); write x fp32 + xb bf16
    {
        float bv[2], gl[2], bl[2];
        #pragma unroll
        for (int ni = 0; ni < 2; ++ni) {
            const int col = wid * 32 + ni * 16 + c;
            bv[ni] = b2[col]; gl[ni] = g2[col]; bl[ni] = be2[col];
        }
        #pragma unroll
        for (int j = 0; j < 4; ++j) {
            const int row = g * 4 + j;
            float s = 0.f;
            #pragma unroll
            for (int ni = 0; ni < 2; ++ni) {
                float vv = acc[ni][j] + bv[ni] + res[ni][j];
                acc[ni][j] = vv;
                s += vv;
            }
            #pragma unroll
            for (int off = 1; off < 16; off <<= 1) s += __shfl_xor(s, off);
            if (c == 0) rsum[wid][row] = s;
        }
        __syncthreads();
        if (tid < 16)
            mval[tid] = (rsum[0][tid] + rsum[1][tid] + rsum[2][tid] + rsum[3][tid]
                       + rsum[4][tid] + rsum[5][tid] + rsum[6][tid] + rsum[7][tid])
                        * (1.f / 256);
        __syncthreads();
        #pragma unroll
        for (int j = 0; j < 4; ++j) {
            const int row = g * 4 + j;
            const float mean = mval[row];
            float q = 0.f;
            #pragma unroll
            for (int ni = 0; ni < 2; ++ni) {
                const float d = acc[ni][j] - mean;
                q += d * d;
            }
            #pragma unroll
            for (int off = 1; off < 16; off <<= 1) q += __shfl_xor(q, off);
            if (c == 0) rsq[wid][row] = q;
        }
        __syncthreads();
        if (tid < 16) {
            const float q = rsq[0][tid] + rsq[1][tid] + rsq[2][tid] + rsq[3][tid]
                          + rsq[4][tid] + rsq[5][tid] + rsq[6][tid] + rsq[7][tid];
            ival[tid] = rsqrtf(q * (1.f / 256) + LN_EPS);
        }
        __syncthreads();
        #pragma unroll
        for (int j = 0; j < 4; ++j) {
            const int row = g * 4 + j;
            const float mean = mval[row], inv = ival[row];
            #pragma unroll
            for (int ni = 0; ni < 2; ++ni) {
                const int col = wid * 32 + ni * 16 + c;
                const float y = (acc[ni][j] - mean) * inv * gl[ni] + bl[ni];
                x[(size_t)(m0 + row) * 256 + col] = y;
                xb[(size_t)(m0 + row) * 256 + col] = f2bf(y);
            }
        }
    }
}

// ---------------------------------------------------------------------------
// Flash attention v9: 4 waves (256 thr), QBLK=128 — each wave owns TWO 16-q
// tiles (t=0,1).  LDS ~71KB -> 2 blocks/CU co-resident: block A's barrier /
// vmcnt stalls are covered by block B (the r20 occupancy lesson applied).
// K-frag and V tr16 reads amortized over both q-tiles.  Per-q-row math is
// identical to v8 (same chunk order, MFMA operands, softmax) -> bit-identical.
// ---------------------------------------------------------------------------
__global__ __launch_bounds__(256)
void attn_mfma9(const ushort* __restrict__ qkv, const int* __restrict__ mask,
                ushort* __restrict__ out)
{
    const int tid = threadIdx.x;
    const int lane = tid & 63, wid = tid >> 6;     // 4 waves
    const int g = lane >> 4, c = lane & 15;
    const int work = xcd_swz(blockIdx.x, 256);     // XCD k: bh 4k..4k+3
    const int qblk = work & 7;
    const int bh = work >> 3;
    const int h = bh & (NH - 1), b = bh >> 3;
    const int q0 = qblk * 128 + wid * 32;          // wave owns rows q0..q0+31

    __shared__ __align__(16) ushort Kb[2][128 * 32];    // 16KB [key][32d] swz
    __shared__ __align__(16) ushort Vs[2][2][128][16];  // 16KB [dhalf][key][16d]
    __shared__ __align__(16) ushort Pl[4][2][16][136];  // 34KB per-wave, per-tile
    __shared__ __align__(16) float  sbias[SS];          // 4KB
    __shared__ int mflag[4];

    const ushort* base  = qkv + (size_t)b * SS * 768;
    const ushort* kbase = base + DMODEL + h * HDIM;
    const ushort* vbase = base + 2 * DMODEL + h * HDIM;

    {   // mask bias + per-wave "any masked" flag (256 thr x 4 ints)
        const int i = tid * 4;
        const int4 mv = *reinterpret_cast<const int4*>(mask + b * SS + i);
        float4 bv;
        bv.x = mv.x ? 0.f : -3.4e38f;
        bv.y = mv.y ? 0.f : -3.4e38f;
        bv.z = mv.z ? 0.f : -3.4e38f;
        bv.w = mv.w ? 0.f : -3.4e38f;
        *reinterpret_cast<float4*>(&sbias[i]) = bv;
        const int miss = __any(!(mv.x && mv.y && mv.z && mv.w));
        if (lane == 0) mflag[wid] = miss;
    }

    // Q fragments for the wave's two 16-row tiles
    bf16x8 qfrag[2];
    #pragma unroll
    for (int t = 0; t < 2; ++t)
        qfrag[t] = *(const bf16x8*)(
            base + (size_t)(q0 + t * 16 + c) * 768 + h * HDIM + g * 8);

    // staging: 256 thr; each K/V chunk = 8KB -> 2 asyncs per thread each.
    const int o16 = tid * 16;

    #define STAGE(buf, koff)                                                     \
        do {                                                                     \
            _Pragma("unroll")                                                    \
            for (int it = 0; it < 2; ++it) {                                     \
                const int off = o16 + it * 4096;                                 \
                const int krow = off >> 6;                                       \
                const int kin  = (off & 63) ^ ((krow & 3) << 4);                 \
                async_ld16(kbase + (size_t)((koff) + krow) * 768 + (kin >> 1),   \
                           (char*)&Kb[buf][0] + off);                            \
                const int vhalf = off >> 12;                                     \
                const int vkey  = (off & 4095) >> 5;                             \
                const int vd    = vhalf * 16 + (((off >> 4) & 1) << 3);          \
                async_ld16(vbase + (size_t)((koff) + vkey) * 768 + vd,           \
                           (char*)&Vs[buf][0][0][0] + off);                      \
            }                                                                    \
        } while (0)

    STAGE(0, 0);
    lgkm0();
    raw_barrier();
    const int anyMasked = mflag[0] | mflag[1] | mflag[2] | mflag[3];

    float m[2] = { -1e30f, -1e30f }, lpart[2] = { 0.f, 0.f };
    f32x4 o0[2] = {}, o1[2] = {};
    const f32x4 zf = {0.f, 0.f, 0.f, 0.f};

    for (int tt = 0; tt < 8; ++tt) {
        const int cur = tt & 1;
        if (tt < 7) { STAGE(cur ^ 1, (tt + 1) * 128); vmcnt_wait<4>(); }
        else        { vmcnt_wait<0>(); }
        raw_barrier();

        // ---- S^T tiles: K-frag loaded once, used for both q-tiles
        f32x4 s[2][8];
        __builtin_amdgcn_s_setprio(1);
        #pragma unroll
        for (int kt = 0; kt < 8; ++kt) {
            const int row = kt * 16 + c;
            const bf16x8 kf = *(const bf16x8*)((const char*)&Kb[cur][0]
                + row * 64 + ((g * 16) ^ ((c & 3) << 4)));
            s[0][kt] = __builtin_amdgcn_mfma_f32_16x16x32_bf16(kf, qfrag[0], zf, 0, 0, 0);
            s[1][kt] = __builtin_amdgcn_mfma_f32_16x16x32_bf16(kf, qfrag[1], zf, 0, 0, 0);
        }
        __builtin_amdgcn_s_setprio(0);

        if (anyMasked) {
            #pragma unroll
            for (int kt = 0; kt < 8; ++kt) {
                const f32x4 bv = *reinterpret_cast<const f32x4*>(
                    &sbias[tt * 128 + kt * 16 + g * 4]);
                #pragma unroll
                for (int r = 0; r < 4; ++r) {
                    s[0][kt][r] += bv[r];
                    s[1][kt][r] += bv[r];
                }
            }
        }

        // ---- V tr16 reads hoisted; shared by both q-tiles
        union UU { s16x4 h[2]; bf16x8 v; };
        UU u0[4], u1[4];
        #pragma unroll
        for (int ks = 0; ks < 4; ++ks) {
            const int vr0 = ks * 32 + g * 8;
            u0[ks].h[0] = tr16(&Vs[cur][0][vr0][c]);
            u0[ks].h[1] = tr16(&Vs[cur][0][vr0 + 4][c]);
            u1[ks].h[0] = tr16(&Vs[cur][1][vr0][c]);
            u1[ks].h[1] = tr16(&Vs[cur][1][vr0 + 4][c]);
        }

        // ---- online softmax per q-tile (identical math to v8)
        #pragma unroll
        for (int t = 0; t < 2; ++t) {
            float mx = fmaxf(fmaxf(s[t][0][0], s[t][0][1]),
                             fmaxf(s[t][0][2], s[t][0][3]));
            #pragma unroll
            for (int kt = 1; kt < 8; ++kt)
                mx = fmaxf(mx, fmaxf(fmaxf(s[t][kt][0], s[t][kt][1]),
                                     fmaxf(s[t][kt][2], s[t][kt][3])));
            if (!__all(mx <= m[t] + 8.f)) {
                float fm = fmaxf(mx, __shfl_xor(mx, 16));
                fm = fmaxf(fm, __shfl_xor(fm, 32));
                const float mn = fmaxf(m[t], fm);
                const float sc = __expf(m[t] - mn);
                m[t] = mn;
                lpart[t] *= sc;
                float scr[4];
                #pragma unroll
                for (int r = 0; r < 4; ++r) scr[r] = __shfl(sc, g * 4 + r);
                #pragma unroll
                for (int r = 0; r < 4; ++r) { o0[t][r] *= scr[r]; o1[t][r] *= scr[r]; }
            }

            float ls = 0.f;
            #pragma unroll
            for (int kt = 0; kt < 8; ++kt) {
                const float p0 = __expf(s[t][kt][0] - m[t]);
                const float p1 = __expf(s[t][kt][1] - m[t]);
                const float p2 = __expf(s[t][kt][2] - m[t]);
                const float p3 = __expf(s[t][kt][3] - m[t]);
                ls += (p0 + p1) + (p2 + p3);
                uint2 pk2 = make_uint2(pack2(p0, p1), pack2(p2, p3));
                *reinterpret_cast<uint2*>(&Pl[wid][t][c][kt * 16 + g * 4]) = pk2;
            }
            lpart[t] += ls;
        }

        // ---- PV: pure MFMA chain, V in regs shared across tiles
        tr_fence();
        __builtin_amdgcn_s_setprio(1);
        #pragma unroll
        for (int ks = 0; ks < 4; ++ks) {
            #pragma unroll
            for (int t = 0; t < 2; ++t) {
                const bf16x8 pa = *(const bf16x8*)&Pl[wid][t][c][ks * 32 + g * 8];
                o0[t] = __builtin_amdgcn_mfma_f32_16x16x32_bf16(pa, u0[ks].v, o0[t], 0, 0, 0);
                o1[t] = __builtin_amdgcn_mfma_f32_16x16x32_bf16(pa, u1[ks].v, o1[t], 0, 0, 0);
            }
        }
        __builtin_amdgcn_s_setprio(0);
        raw_barrier();
    }
    #undef STAGE

    // ---- finalize both tiles
    #pragma unroll
    for (int t = 0; t < 2; ++t) {
        float lsum = lpart[t];
        lsum += __shfl_xor(lsum, 16);
        lsum += __shfl_xor(lsum, 32);
        const float rs = 1.f / lsum;
        float inv[4];
        #pragma unroll
        for (int r = 0; r < 4; ++r) inv[r] = __shfl(rs, g * 4 + r);
        #pragma unroll
        for (int r = 0; r < 4; ++r) {
            ushort* op = out + (size_t)(b * SS + q0 + t * 16 + g * 4 + r) * DMODEL
                       + h * HDIM;
            op[c]      = f2bf(o0[t][r] * inv[r]);
            op[16 + c] = f2bf(o1[t][r] * inv[r]);
        }
    }
}

// ---------------------------------------------------------------------------
extern "C" void kernel_launch(void* const* d_in, const int* in_sizes, int n_in,
                              void* d_out, int out_size, void* d_ws, size_t ws_size,
                              hipStream_t stream)
{
    const float* x_in   = (const float*)d_in[0];
    const int*   maskp  = (const int*)d_in[1];
    const float* qkv_w  = (const float*)d_in[2];
    const float* qkv_b  = (const float*)d_in[3];
    const float* fc_w   = (const float*)d_in[4];
    const float* fc_b   = (const float*)d_in[5];
    const float* ln1_g  = (const float*)d_in[6];
    const float* ln1_b  = (const float*)d_in[7];
    const float* ln2_g  = (const float*)d_in[8];
    const float* ln2_b  = (const float*)d_in[9];
    const float* ff1_w  = (const float*)d_in[10];
    const float* ff1_b  = (const float*)d_in[11];
    const float* ff2_w  = (const float*)d_in[12];
    const float* ff2_b  = (const float*)d_in[13];

    float* x = (float*)d_out;                       // [4096,256] fp32 residual

    ushort* wt_qkv = (ushort*)d_ws;                 // [L][768][256]
    ushort* wt_fc  = wt_qkv + (size_t)NL * 768 * 256;
    ushort* wt_ff1 = wt_fc  + (size_t)NL * 256 * 256;
    ushort* wt_ff2 = wt_ff1 + (size_t)NL * 1024 * 256;
    ushort* big    = wt_ff2 + (size_t)NL * 256 * 1024;  // qkv_bf (6MB)
    ushort* attn_bf= big + (size_t)MROWS * FFDIM;
    ushort* x_bf   = attn_bf + (size_t)MROWS * DMODEL;

    wconv_all<<<dim3(768, 1, NL), 256, 0, stream>>>(
        qkv_w, fc_w, ff1_w, ff2_w, wt_qkv, wt_fc, wt_ff1, wt_ff2);
    convert_x<<<dim3(MROWS * DMODEL / 1024), 256, 0, stream>>>(x_in, x, x_bf);

    for (int l = 0; l < NL; ++l) {
        // qkv (bf16 out) [4096,768] — 64x64 tile, 768 blocks = 3/CU balanced
        gemm_mfma<64, 64, 2, 2, 0, 1><<<dim3(12, 64), 256, 0, stream>>>(
            x_bf, wt_qkv + (size_t)l * 768 * 256, qkv_b + l * 768,
            nullptr, big, 768, 256);
        // attention -> attn_bf [4096,256] bf16 (4 waves, 2 blocks/CU)
        attn_mfma9<<<dim3(256), 256, 0, stream>>>(big, maskp, attn_bf);
        // fused fc+LN1+ff1+ff2+LN2 (8 compute waves) -> x, x_bf
        mlp_fused<<<dim3(256), 512, 0, stream>>>(
            attn_bf, wt_fc + (size_t)l * 256 * 256, fc_b + l * 256,
            ln1_g + l * DMODEL, ln1_b + l * DMODEL,
            wt_ff1 + (size_t)l * 1024 * 256, ff1_b + l * FFDIM,
            wt_ff2 + (size_t)l * 256 * 1024, ff2_b + l * DMODEL,
            ln2_g + l * DMODEL, ln2_b + l * DMODEL, x, x_bf);
    }
}

// Round 24
// 209.163 us; speedup vs baseline: 1.0712x; 1.0712x over previous
//
#include <hip/hip_runtime.h>
#include <hip/hip_bf16.h>
#include <math.h>

#define NL 4
#define DMODEL 256
#define NH 8
#define FFDIM 1024
#define BB 4
#define SS 1024
#define HDIM 32
#define MROWS (BB * SS)   // 4096
#define LN_EPS 1e-5f

typedef __bf16 bf16x8 __attribute__((ext_vector_type(8)));
typedef float f32x4 __attribute__((ext_vector_type(4)));
typedef short s16x4 __attribute__((ext_vector_type(4)));
typedef unsigned int u32;

__device__ __forceinline__ ushort f2bf(float f) {
    uint u = __builtin_bit_cast(uint, f);
    u += 0x7fff + ((u >> 16) & 1);          // round-to-nearest-even
    return (ushort)(u >> 16);
}
__device__ __forceinline__ uint pack2(float a, float b) {
    return (uint)f2bf(a) | ((uint)f2bf(b) << 16);
}

// XCD-chunked block swizzle (T1).  nwg % 8 == 0 -> bijective.
__device__ __forceinline__ int xcd_swz(int bid, int nwg) {
    return (bid & 7) * (nwg >> 3) + (bid >> 3);
}

// counted vmcnt wait (T4): allow N newest loads outstanding; older ones done.
template<int N> __device__ __forceinline__ void vmcnt_wait() {
    asm volatile("s_waitcnt vmcnt(%0)" :: "n"(N) : "memory");
}
// raw barrier: NO implicit vmcnt(0) drain (unlike __syncthreads()).
__device__ __forceinline__ void raw_barrier() {
    asm volatile("s_barrier" ::: "memory");
}
__device__ __forceinline__ void lgkm0() {
    asm volatile("s_waitcnt lgkmcnt(0)" ::: "memory");
}

// async global->LDS, 16B per lane (wave-uniform LDS base + lane*16 layout)
__device__ __forceinline__ void async_ld16(const void* g, void* l) {
    __builtin_amdgcn_global_load_lds(
        (const __attribute__((address_space(1))) u32*)g,
        (__attribute__((address_space(3))) u32*)l, 16, 0, 0);
}

// ds_read_b64_tr_b16: per-lane byte addr A -> 4 bf16 at A, A+32B, A+64B, A+96B
#if __has_builtin(__builtin_amdgcn_ds_read_tr16_b64)
#define TR_BUILTIN 1
#else
#define TR_BUILTIN 0
#endif

__device__ __forceinline__ s16x4 tr16(const ushort* p) {
    __attribute__((address_space(3))) s16x4* ap =
        (__attribute__((address_space(3))) s16x4*)p;
#if TR_BUILTIN
    return __builtin_amdgcn_ds_read_tr16_b64(ap);
#else
    s16x4 r;
    asm volatile("ds_read_b64_tr_b16 %0, %1" : "=v"(r) : "v"(ap) : "memory");
    return r;
#endif
}
__device__ __forceinline__ void tr_fence() {
#if !TR_BUILTIN
    asm volatile("s_waitcnt lgkmcnt(0)" ::: "memory");
    __builtin_amdgcn_sched_barrier(0);
#endif
}

// ---------------------------------------------------------------------------
// All weight transposes in one dispatch. Flat tile id -> {weight, tile}.
// ---------------------------------------------------------------------------
__global__ __launch_bounds__(256)
void wconv_all(const float* __restrict__ qkv_w, const float* __restrict__ fc_w,
               const float* __restrict__ ff1_w, const float* __restrict__ ff2_w,
               ushort* __restrict__ wq, ushort* __restrict__ wfc,
               ushort* __restrict__ wf1, ushort* __restrict__ wf2)
{
    const int l = blockIdx.z;
    int t = blockIdx.x;
    const float* src; ushort* dst; int K, N, nx;
    if (t < 192)      {          src = qkv_w; dst = wq;  K = 256;  N = 768;  nx = 24; }
    else if (t < 256) { t -= 192; src = fc_w;  dst = wfc; K = 256;  N = 256;  nx = 8; }
    else if (t < 512) { t -= 256; src = ff1_w; dst = wf1; K = 256;  N = 1024; nx = 32; }
    else              { t -= 512; src = ff2_w; dst = wf2; K = 1024; N = 256;  nx = 8; }
    src += (size_t)l * K * N;
    dst += (size_t)l * K * N;
    const int n0 = (t % nx) * 32, k0 = (t / nx) * 32;

    __shared__ ushort tt[32][33];
    const int tn = threadIdx.x & 31, tk8 = threadIdx.x >> 5;
    #pragma unroll
    for (int i = 0; i < 4; ++i)
        tt[tn][tk8 + i * 8] = f2bf(src[(size_t)(k0 + tk8 + i * 8) * N + n0 + tn]);
    __syncthreads();
    #pragma unroll
    for (int i = 0; i < 4; ++i)
        dst[(size_t)(n0 + tk8 + i * 8) * K + k0 + tn] = tt[tk8 + i * 8][tn];
}

// ---------------------------------------------------------------------------
// x_in fp32 -> x fp32 (d_out residual stream) + x_bf bf16 mirror
// ---------------------------------------------------------------------------
__global__ __launch_bounds__(256)
void convert_x(const float* __restrict__ xin, float* __restrict__ x,
               ushort* __restrict__ xb)
{
    const size_t i = ((size_t)blockIdx.x * 256 + threadIdx.x) * 4;
    const float4 v = *reinterpret_cast<const float4*>(xin + i);
    *reinterpret_cast<float4*>(x + i) = v;
    uint2 p = make_uint2(pack2(v.x, v.y), pack2(v.z, v.w));
    *reinterpret_cast<uint2*>(xb + i) = p;
}

// ---------------------------------------------------------------------------
// MFMA GEMM, 2-phase dbuf, counted vmcnt + raw barriers, LDS swizzle + XCD
// swizzle (r13/r14 verified).  Per-layer qkv.
// ---------------------------------------------------------------------------
template<int BM, int BN, int WM, int WN, int ACT, int OBF>
__global__ __launch_bounds__(256)
void gemm_mfma(const ushort* __restrict__ A, const ushort* __restrict__ WT,
               const float* __restrict__ bias, float* __restrict__ Cf,
               ushort* __restrict__ Cb, int N, int K)
{
    constexpr int BK = 64;
    constexpr int WR = BM / WM;
    constexpr int WC = BN / WN;
    constexpr int MR = WR / 16, NR = WC / 16;
    constexpr int LSTG = BM / 32 + BN / 32;
    __shared__ __align__(16) ushort As[2][BM * BK];
    __shared__ __align__(16) ushort Bs[2][BN * BK];

    const int tid = threadIdx.x;
    const int lin = blockIdx.y * gridDim.x + blockIdx.x;
    const int work = xcd_swz(lin, gridDim.x * gridDim.y);
    const int m0 = (work / gridDim.x) * BM, n0 = (work % gridDim.x) * BN;
    const int wid = tid >> 6, lane = tid & 63;
    const int g = lane >> 4, c = lane & 15;
    const int wr = wid / WN, wc = wid % WN;

    auto stage = [&](int buf, int k0) {
        #pragma unroll
        for (int it = 0; it < (BM * BK * 2) / 4096; ++it) {
            const int o = tid * 16 + it * 4096;
            const int r = o >> 7;
            const int cb = (o & 127) ^ ((r & 7) << 4);
            async_ld16(A + (size_t)(m0 + r) * K + k0 + (cb >> 1),
                       (char*)&As[buf][0] + o);
        }
        #pragma unroll
        for (int it = 0; it < (BN * BK * 2) / 4096; ++it) {
            const int o = tid * 16 + it * 4096;
            const int r = o >> 7;
            const int cb = (o & 127) ^ ((r & 7) << 4);
            async_ld16(WT + (size_t)(n0 + r) * K + k0 + (cb >> 1),
                       (char*)&Bs[buf][0] + o);
        }
    };

    f32x4 acc[MR][NR] = {};

    stage(0, 0);

    int cur = 0;
    for (int k0 = 0; k0 < K; k0 += BK, cur ^= 1) {
        if (k0 + BK < K) { stage(cur ^ 1, k0 + BK); vmcnt_wait<LSTG>(); }
        else             { vmcnt_wait<0>(); }
        raw_barrier();

        #pragma unroll
        for (int ks = 0; ks < 2; ++ks) {
            bf16x8 af[MR], bfr[NR];
            #pragma unroll
            for (int mi = 0; mi < MR; ++mi) {
                const int row = wr * WR + mi * 16 + c;
                af[mi] = *(const bf16x8*)((const char*)&As[cur][0]
                    + row * 128 + ((ks * 64 + g * 16) ^ ((row & 7) << 4)));
            }
            #pragma unroll
            for (int ni = 0; ni < NR; ++ni) {
                const int row = wc * WC + ni * 16 + c;
                bfr[ni] = *(const bf16x8*)((const char*)&Bs[cur][0]
                    + row * 128 + ((ks * 64 + g * 16) ^ ((row & 7) << 4)));
            }
            #pragma unroll
            for (int mi = 0; mi < MR; ++mi)
                #pragma unroll
                for (int ni = 0; ni < NR; ++ni)
                    acc[mi][ni] = __builtin_amdgcn_mfma_f32_16x16x32_bf16(
                        af[mi], bfr[ni], acc[mi][ni], 0, 0, 0);
        }
        raw_barrier();
    }

    float bv[NR];
    #pragma unroll
    for (int ni = 0; ni < NR; ++ni)
        bv[ni] = bias[n0 + wc * WC + ni * 16 + c];

    #pragma unroll
    for (int mi = 0; mi < MR; ++mi) {
        #pragma unroll
        for (int j = 0; j < 4; ++j) {
            const int row = m0 + wr * WR + mi * 16 + g * 4 + j;
            #pragma unroll
            for (int ni = 0; ni < NR; ++ni) {
                float v = acc[mi][ni][j] + bv[ni];
                if (ACT) v = fmaxf(v, 0.f);
                const int col = n0 + wc * WC + ni * 16 + c;
                if (OBF) Cb[(size_t)row * N + col] = f2bf(v);
                else     Cf[(size_t)row * N + col] = v;
            }
        }
    }
}

// ---------------------------------------------------------------------------
// Fused MLP-chain v4 (r20 verified optimum): 8 COMPUTE waves (512 thr), each
// wave owns 32 output columns.  Double-buffered Bs, two raw barriers/step,
// depth-1 counted vmcnt with stage-before-wait ordering.  2 waves/SIMD.
// ---------------------------------------------------------------------------
__global__ __launch_bounds__(512)
void mlp_fused(const ushort* __restrict__ Aattn, const ushort* __restrict__ Wfc,
               const float* __restrict__ bfc, const float* __restrict__ g1,
               const float* __restrict__ be1, const ushort* __restrict__ W1,
               const float* __restrict__ b1, const ushort* __restrict__ W2,
               const float* __restrict__ b2, const float* __restrict__ g2,
               const float* __restrict__ be2, float* __restrict__ x,
               ushort* __restrict__ xb)
{
    __shared__ __align__(16) ushort As[2][16 * 64];     // 4KB
    __shared__ __align__(16) ushort Bs[2][256 * 64];    // 64KB
    __shared__ __align__(16) ushort ybf[16 * 256];      // 8KB  (swizzled)
    __shared__ __align__(16) ushort hbuf[16 * 1024];    // 32KB (swizzled)
    __shared__ float rsum[8][16], rsq[8][16], mval[16], ival[16];

    const int tid = threadIdx.x;
    const int m0 = blockIdx.x * 16;
    const int wid = tid >> 6, lane = tid & 63;
    const int g = lane >> 4, c = lane & 15;

    auto stageB = [&](int buf, const ushort* src, int ldk) {
        #pragma unroll
        for (int it = 0; it < 4; ++it) {        // 512 thr x 4 x 16B = 32KB
            const int o = tid * 16 + it * 8192;
            const int r = o >> 7;
            const int cb = (o & 127) ^ ((r & 7) << 4);
            async_ld16(src + (size_t)r * ldk + (cb >> 1), (char*)&Bs[buf][0] + o);
        }
    };
    auto stageA = [&](int buf, int k0) {
        if (tid < 128) {
            const int o = tid * 16;
            const int r = o >> 7;
            const int cb = (o & 127) ^ ((r & 7) << 4);
            async_ld16(Aattn + (size_t)(m0 + r) * 256 + k0 + (cb >> 1),
                       (char*)&As[buf][0] + o);
        }
    };

    f32x4 acc[2] = {};

    // ================= phase 1: fc (K=256, 4 steps) =================
    stageA(0, 0); stageB(0, Wfc, 256);
    int cur = 0;
    #pragma unroll
    for (int k = 0; k < 4; ++k, cur ^= 1) {
        if (k < 3) {
            stageA(cur ^ 1, (k + 1) * 64);
            stageB(cur ^ 1, Wfc + (k + 1) * 64, 256);
            if (tid < 128) vmcnt_wait<5>(); else vmcnt_wait<4>();
        } else {
            stageB(cur ^ 1, W1, 256);           // prefetch ff1 step 0
            vmcnt_wait<4>();
        }
        raw_barrier();
        #pragma unroll
        for (int ks = 0; ks < 2; ++ks) {
            const bf16x8 af = *(const bf16x8*)((const char*)&As[cur][0]
                + c * 128 + ((ks * 64 + g * 16) ^ ((c & 7) << 4)));
            #pragma unroll
            for (int ni = 0; ni < 2; ++ni) {
                const int row = wid * 32 + ni * 16 + c;
                const bf16x8 bf = *(const bf16x8*)((const char*)&Bs[cur][0]
                    + row * 128 + ((ks * 64 + g * 16) ^ ((row & 7) << 4)));
                acc[ni] = __builtin_amdgcn_mfma_f32_16x16x32_bf16(af, bf, acc[ni], 0, 0, 0);
            }
        }
        raw_barrier();
    }
    // cur == 0; ff1 step0 staged in buf 0.

    // ---- LN1 epilogue: y = LN(acc + bfc + x_res); res regs + ybf LDS
    float res[2][4];
    {
        float bv[2], gl[2], bl[2];
        #pragma unroll
        for (int ni = 0; ni < 2; ++ni) {
            const int col = wid * 32 + ni * 16 + c;
            bv[ni] = bfc[col]; gl[ni] = g1[col]; bl[ni] = be1[col];
        }
        #pragma unroll
        for (int j = 0; j < 4; ++j) {
            const int row = g * 4 + j;
            float s = 0.f;
            #pragma unroll
            for (int ni = 0; ni < 2; ++ni) {
                const int col = wid * 32 + ni * 16 + c;
                float vv = acc[ni][j] + bv[ni] + x[(size_t)(m0 + row) * 256 + col];
                acc[ni][j] = vv;
                s += vv;
            }
            #pragma unroll
            for (int off = 1; off < 16; off <<= 1) s += __shfl_xor(s, off);
            if (c == 0) rsum[wid][row] = s;
        }
        __syncthreads();
        if (tid < 16)
            mval[tid] = (rsum[0][tid] + rsum[1][tid] + rsum[2][tid] + rsum[3][tid]
                       + rsum[4][tid] + rsum[5][tid] + rsum[6][tid] + rsum[7][tid])
                        * (1.f / 256);
        __syncthreads();
        #pragma unroll
        for (int j = 0; j < 4; ++j) {
            const int row = g * 4 + j;
            const float mean = mval[row];
            float q = 0.f;
            #pragma unroll
            for (int ni = 0; ni < 2; ++ni) {
                const float d = acc[ni][j] - mean;
                q += d * d;
            }
            #pragma unroll
            for (int off = 1; off < 16; off <<= 1) q += __shfl_xor(q, off);
            if (c == 0) rsq[wid][row] = q;
        }
        __syncthreads();
        if (tid < 16) {
            const float q = rsq[0][tid] + rsq[1][tid] + rsq[2][tid] + rsq[3][tid]
                          + rsq[4][tid] + rsq[5][tid] + rsq[6][tid] + rsq[7][tid];
            ival[tid] = rsqrtf(q * (1.f / 256) + LN_EPS);
        }
        __syncthreads();
        #pragma unroll
        for (int j = 0; j < 4; ++j) {
            const int row = g * 4 + j;
            const float mean = mval[row], inv = ival[row];
            #pragma unroll
            for (int ni = 0; ni < 2; ++ni) {
                const int col = wid * 32 + ni * 16 + c;
                const float y = (acc[ni][j] - mean) * inv * gl[ni] + bl[ni];
                res[ni][j] = y;
                const int byteo = row * 512 + ((col * 2) ^ ((row & 7) << 4));
                *(ushort*)((char*)ybf + byteo) = f2bf(y);
                acc[ni][j] = 0.f;
            }
        }
    }
    lgkm0();
    raw_barrier();          // ybf visible to all waves

    // ================= phase 2: ff1 (4 nt-tiles x 4 k-steps) =================
    #pragma unroll 1
    for (int s = 0; s < 16; ++s, cur ^= 1) {
        const int kk = s & 3;
        if (s < 15) {
            const int s2 = s + 1;
            stageB(cur ^ 1, W1 + (size_t)((s2 >> 2) * 256) * 256 + (s2 & 3) * 64, 256);
            vmcnt_wait<4>();
        } else {
            stageB(cur ^ 1, W2, 1024);          // prefetch ff2 step 0
            vmcnt_wait<4>();
        }
        raw_barrier();
        #pragma unroll
        for (int ks = 0; ks < 2; ++ks) {
            const int kbyte = (kk * 64 + ks * 32 + g * 8) * 2;
            const bf16x8 af = *(const bf16x8*)((const char*)ybf
                + c * 512 + (kbyte ^ ((c & 7) << 4)));
            #pragma unroll
            for (int ni = 0; ni < 2; ++ni) {
                const int row = wid * 32 + ni * 16 + c;
                const bf16x8 bf = *(const bf16x8*)((const char*)&Bs[cur][0]
                    + row * 128 + ((ks * 64 + g * 16) ^ ((row & 7) << 4)));
                acc[ni] = __builtin_amdgcn_mfma_f32_16x16x32_bf16(af, bf, acc[ni], 0, 0, 0);
            }
        }
        raw_barrier();
        if (kk == 3) {      // h epilogue for this nt-tile
            const int nt = s >> 2;
            #pragma unroll
            for (int j = 0; j < 4; ++j) {
                const int row = g * 4 + j;
                #pragma unroll
                for (int ni = 0; ni < 2; ++ni) {
                    const int col = nt * 256 + wid * 32 + ni * 16 + c;
                    const float h = fmaxf(acc[ni][j] + b1[col], 0.f);
                    const int byteo = row * 2048 + (((col & 1023) * 2) ^ ((row & 7) << 4));
                    *(ushort*)((char*)hbuf + byteo) = f2bf(h);
                    acc[ni][j] = 0.f;
                }
            }
        }
    }
    lgkm0();
    raw_barrier();          // hbuf visible

    // ================= phase 3: ff2 (K=1024, 16 steps) =================
    #pragma unroll 1
    for (int s = 0; s < 16; ++s, cur ^= 1) {
        if (s < 15) { stageB(cur ^ 1, W2 + (s + 1) * 64, 1024); vmcnt_wait<4>(); }
        else        { vmcnt_wait<0>(); }
        raw_barrier();
        #pragma unroll
        for (int ks = 0; ks < 2; ++ks) {
            const int kbyte = (s * 64 + ks * 32 + g * 8) * 2;
            const bf16x8 af = *(const bf16x8*)((const char*)hbuf
                + c * 2048 + (kbyte ^ ((c & 7) << 4)));
            #pragma unroll
            for (int ni = 0; ni < 2; ++ni) {
                const int row = wid * 32 + ni * 16 + c;
                const bf16x8 bf = *(const bf16x8*)((const char*)&Bs[cur][0]
                    + row * 128 + ((ks * 64 + g * 16) ^ ((row & 7) << 4)));
                acc[ni] = __builtin_amdgcn_mfma_f32_16x16x32_bf16(af, bf, acc[ni], 0, 0, 0);
            }
        }
        raw_barrier();
    }

    // ---- LN2 epilogue: x = LN(acc + b2 + res); write x fp32 + xb bf16
    {
        float bv[2], gl[2], bl[2];
        #pragma unroll
        for (int ni = 0; ni < 2; ++ni) {
            const int col = wid * 32 + ni * 16 + c;
            bv[ni] = b2[col]; gl[ni] = g2[col]; bl[ni] = be2[col];
        }
        #pragma unroll
        for (int j = 0; j < 4; ++j) {
            const int row = g * 4 + j;
            float s = 0.f;
            #pragma unroll
            for (int ni = 0; ni < 2; ++ni) {
                float vv = acc[ni][j] + bv[ni] + res[ni][j];
                acc[ni][j] = vv;
                s += vv;
            }
            #pragma unroll
            for (int off = 1; off < 16; off <<= 1) s += __shfl_xor(s, off);
            if (c == 0) rsum[wid][row] = s;
        }
        __syncthreads();
        if (tid < 16)
            mval[tid] = (rsum[0][tid] + rsum[1][tid] + rsum[2][tid] + rsum[3][tid]
                       + rsum[4][tid] + rsum[5][tid] + rsum[6][tid] + rsum[7][tid])
                        * (1.f / 256);
        __syncthreads();
        #pragma unroll
        for (int j = 0; j < 4; ++j) {
            const int row = g * 4 + j;
            const float mean = mval[row];
            float q = 0.f;
            #pragma unroll
            for (int ni = 0; ni < 2; ++ni) {
                const float d = acc[ni][j] - mean;
                q += d * d;
            }
            #pragma unroll
            for (int off = 1; off < 16; off <<= 1) q += __shfl_xor(q, off);
            if (c == 0) rsq[wid][row] = q;
        }
        __syncthreads();
        if (tid < 16) {
            const float q = rsq[0][tid] + rsq[1][tid] + rsq[2][tid] + rsq[3][tid]
                          + rsq[4][tid] + rsq[5][tid] + rsq[6][tid] + rsq[7][tid];
            ival[tid] = rsqrtf(q * (1.f / 256) + LN_EPS);
        }
        __syncthreads();
        #pragma unroll
        for (int j = 0; j < 4; ++j) {
            const int row = g * 4 + j;
            const float mean = mval[row], inv = ival[row];
            #pragma unroll
            for (int ni = 0; ni < 2; ++ni) {
                const int col = wid * 32 + ni * 16 + c;
                const float y = (acc[ni][j] - mean) * inv * gl[ni] + bl[ni];
                x[(size_t)(m0 + row) * 256 + col] = y;
                xb[(size_t)(m0 + row) * 256 + col] = f2bf(y);
            }
        }
    }
}

// ---------------------------------------------------------------------------
// Flash attention v8 (r13 verified, unchanged): 8 waves, QBLK=128, KVBLK=128
// dbuf, grid 256, hoisted tr16, counted vmcnt / raw barriers.
// ---------------------------------------------------------------------------
__global__ __launch_bounds__(512)
void attn_mfma8(const ushort* __restrict__ qkv, const int* __restrict__ mask,
                ushort* __restrict__ out)
{
    const int tid = threadIdx.x;
    const int lane = tid & 63, wid = tid >> 6;
    const int g = lane >> 4, c = lane & 15;
    const int work = xcd_swz(blockIdx.x, 256);   // XCD k: bh 4k..4k+3
    const int qblk = work & 7;
    const int bh = work >> 3;
    const int h = bh & (NH - 1), b = bh >> 3;
    const int q0 = qblk * 128 + wid * 16;

    __shared__ __align__(16) ushort Kb[2][128 * 32];
    __shared__ __align__(16) ushort Vs[2][2][128][16];
    __shared__ __align__(16) ushort Pl[8][16][136];
    __shared__ __align__(16) float  sbias[SS];
    __shared__ int mflag[8];

    const ushort* base  = qkv + (size_t)b * SS * 768;
    const ushort* kbase = base + DMODEL + h * HDIM;
    const ushort* vbase = base + 2 * DMODEL + h * HDIM;

    {
        const int i = tid * 2;
        const int2 mv = *reinterpret_cast<const int2*>(mask + b * SS + i);
        float2 bv;
        bv.x = mv.x ? 0.f : -3.4e38f;
        bv.y = mv.y ? 0.f : -3.4e38f;
        *reinterpret_cast<float2*>(&sbias[i]) = bv;
        const int miss = __any(!(mv.x && mv.y));
        if (lane == 0) mflag[wid] = miss;
    }

    const bf16x8 qfrag = *(const bf16x8*)(
        base + (size_t)(q0 + c) * 768 + h * HDIM + g * 8);

    const int o16   = tid * 16;
    const int krow  = o16 >> 6;
    const int kin   = (o16 & 63) ^ ((krow & 3) << 4);
    const int vhalf = o16 >> 12;
    const int vkey  = (o16 & 4095) >> 5;
    const int vd    = vhalf * 16 + (((o16 >> 4) & 1) << 3);

    #define STAGE(buf, koff)                                                   \
        do {                                                                   \
            async_ld16(kbase + (size_t)((koff) + krow) * 768 + (kin >> 1),     \
                       (char*)&Kb[buf][0] + o16);                              \
            async_ld16(vbase + (size_t)((koff) + vkey) * 768 + vd,             \
                       (char*)&Vs[buf][0][0][0] + o16);                        \
        } while (0)

    STAGE(0, 0);
    lgkm0();
    raw_barrier();
    const int anyMasked = mflag[0] | mflag[1] | mflag[2] | mflag[3]
                        | mflag[4] | mflag[5] | mflag[6] | mflag[7];

    float m = -1e30f, lpart = 0.f;
    f32x4 o0 = {0.f, 0.f, 0.f, 0.f}, o1 = {0.f, 0.f, 0.f, 0.f};
    const f32x4 zf = {0.f, 0.f, 0.f, 0.f};

    for (int t = 0; t < 8; ++t) {
        const int cur = t & 1;
        if (t < 7) { STAGE(cur ^ 1, (t + 1) * 128); vmcnt_wait<2>(); }
        else       { vmcnt_wait<0>(); }
        raw_barrier();

        f32x4 s[8];
        __builtin_amdgcn_s_setprio(1);
        #pragma unroll
        for (int kt = 0; kt < 8; ++kt) {
            const int row = kt * 16 + c;
            const bf16x8 kf = *(const bf16x8*)((const char*)&Kb[cur][0]
                + row * 64 + ((g * 16) ^ ((c & 3) << 4)));
            s[kt] = __builtin_amdgcn_mfma_f32_16x16x32_bf16(kf, qfrag, zf, 0, 0, 0);
        }
        __builtin_amdgcn_s_setprio(0);

        if (anyMasked) {
            #pragma unroll
            for (int kt = 0; kt < 8; ++kt) {
                const f32x4 bv = *reinterpret_cast<const f32x4*>(
                    &sbias[t * 128 + kt * 16 + g * 4]);
                #pragma unroll
                for (int r = 0; r < 4; ++r) s[kt][r] += bv[r];
            }
        }

        union UU { s16x4 h[2]; bf16x8 v; };
        UU u0[4], u1[4];
        #pragma unroll
        for (int ks = 0; ks < 4; ++ks) {
            const int vr0 = ks * 32 + g * 8;
            u0[ks].h[0] = tr16(&Vs[cur][0][vr0][c]);
            u0[ks].h[1] = tr16(&Vs[cur][0][vr0 + 4][c]);
            u1[ks].h[0] = tr16(&Vs[cur][1][vr0][c]);
            u1[ks].h[1] = tr16(&Vs[cur][1][vr0 + 4][c]);
        }

        float mx = fmaxf(fmaxf(s[0][0], s[0][1]), fmaxf(s[0][2], s[0][3]));
        #pragma unroll
        for (int kt = 1; kt < 8; ++kt)
            mx = fmaxf(mx, fmaxf(fmaxf(s[kt][0], s[kt][1]),
                                 fmaxf(s[kt][2], s[kt][3])));
        if (!__all(mx <= m + 8.f)) {
            float fm = fmaxf(mx, __shfl_xor(mx, 16));
            fm = fmaxf(fm, __shfl_xor(fm, 32));
            const float mn = fmaxf(m, fm);
            const float sc = __expf(m - mn);
            m = mn;
            lpart *= sc;
            float scr[4];
            #pragma unroll
            for (int r = 0; r < 4; ++r) scr[r] = __shfl(sc, g * 4 + r);
            #pragma unroll
            for (int r = 0; r < 4; ++r) { o0[r] *= scr[r]; o1[r] *= scr[r]; }
        }

        float ls = 0.f;
        #pragma unroll
        for (int kt = 0; kt < 8; ++kt) {
            const float p0 = __expf(s[kt][0] - m);
            const float p1 = __expf(s[kt][1] - m);
            const float p2 = __expf(s[kt][2] - m);
            const float p3 = __expf(s[kt][3] - m);
            ls += (p0 + p1) + (p2 + p3);
            uint2 pk2 = make_uint2(pack2(p0, p1), pack2(p2, p3));
            *reinterpret_cast<uint2*>(&Pl[wid][c][kt * 16 + g * 4]) = pk2;
        }
        lpart += ls;

        tr_fence();
        __builtin_amdgcn_s_setprio(1);
        #pragma unroll
        for (int ks = 0; ks < 4; ++ks) {
            const bf16x8 pa = *(const bf16x8*)&Pl[wid][c][ks * 32 + g * 8];
            o0 = __builtin_amdgcn_mfma_f32_16x16x32_bf16(pa, u0[ks].v, o0, 0, 0, 0);
            o1 = __builtin_amdgcn_mfma_f32_16x16x32_bf16(pa, u1[ks].v, o1, 0, 0, 0);
        }
        __builtin_amdgcn_s_setprio(0);
        raw_barrier();
    }
    #undef STAGE

    float lsum = lpart;
    lsum += __shfl_xor(lsum, 16);
    lsum += __shfl_xor(lsum, 32);
    const float rs = 1.f / lsum;
    float inv[4];
    #pragma unroll
    for (int r = 0; r < 4; ++r) inv[r] = __shfl(rs, g * 4 + r);
    #pragma unroll
    for (int r = 0; r < 4; ++r) {
        ushort* op = out + (size_t)(b * SS + q0 + g * 4 + r) * DMODEL + h * HDIM;
        op[c]      = f2bf(o0[r] * inv[r]);
        op[16 + c] = f2bf(o1[r] * inv[r]);
    }
}

// ---------------------------------------------------------------------------
extern "C" void kernel_launch(void* const* d_in, const int* in_sizes, int n_in,
                              void* d_out, int out_size, void* d_ws, size_t ws_size,
                              hipStream_t stream)
{
    const float* x_in   = (const float*)d_in[0];
    const int*   maskp  = (const int*)d_in[1];
    const float* qkv_w  = (const float*)d_in[2];
    const float* qkv_b  = (const float*)d_in[3];
    const float* fc_w   = (const float*)d_in[4];
    const float* fc_b   = (const float*)d_in[5];
    const float* ln1_g  = (const float*)d_in[6];
    const float* ln1_b  = (const float*)d_in[7];
    const float* ln2_g  = (const float*)d_in[8];
    const float* ln2_b  = (const float*)d_in[9];
    const float* ff1_w  = (const float*)d_in[10];
    const float* ff1_b  = (const float*)d_in[11];
    const float* ff2_w  = (const float*)d_in[12];
    const float* ff2_b  = (const float*)d_in[13];

    float* x = (float*)d_out;                       // [4096,256] fp32 residual

    ushort* wt_qkv = (ushort*)d_ws;                 // [L][768][256]
    ushort* wt_fc  = wt_qkv + (size_t)NL * 768 * 256;
    ushort* wt_ff1 = wt_fc  + (size_t)NL * 256 * 256;
    ushort* wt_ff2 = wt_ff1 + (size_t)NL * 1024 * 256;
    ushort* big    = wt_ff2 + (size_t)NL * 256 * 1024;  // qkv_bf (6MB)
    ushort* attn_bf= big + (size_t)MROWS * FFDIM;
    ushort* x_bf   = attn_bf + (size_t)MROWS * DMODEL;

    wconv_all<<<dim3(768, 1, NL), 256, 0, stream>>>(
        qkv_w, fc_w, ff1_w, ff2_w, wt_qkv, wt_fc, wt_ff1, wt_ff2);
    convert_x<<<dim3(MROWS * DMODEL / 1024), 256, 0, stream>>>(x_in, x, x_bf);

    for (int l = 0; l < NL; ++l) {
        // qkv (bf16 out) [4096,768] — 64x64 tile, 768 blocks = 3/CU balanced
        gemm_mfma<64, 64, 2, 2, 0, 1><<<dim3(12, 64), 256, 0, stream>>>(
            x_bf, wt_qkv + (size_t)l * 768 * 256, qkv_b + l * 768,
            nullptr, big, 768, 256);
        // attention -> attn_bf [4096,256] bf16
        attn_mfma8<<<dim3(256), 512, 0, stream>>>(big, maskp, attn_bf);
        // fused fc+LN1+ff1+ff2+LN2 (8 compute waves) -> x, x_bf
        mlp_fused<<<dim3(256), 512, 0, stream>>>(
            attn_bf, wt_fc + (size_t)l * 256 * 256, fc_b + l * 256,
            ln1_g + l * DMODEL, ln1_b + l * DMODEL,
            wt_ff1 + (size_t)l * 1024 * 256, ff1_b + l * FFDIM,
            wt_ff2 + (size_t)l * 256 * 1024, ff2_b + l * DMODEL,
            ln2_g + l * DMODEL, ln2_b + l * DMODEL, x, x_bf);
    }
}